// Round 18
// baseline (347.474 us; speedup 1.0000x reference)
//
#include <hip/hip_runtime.h>
#include <hip/hip_fp16.h>
#include <cstdint>
#include <cstddef>

#define N_NODES 100000
#define N_EDGES 3200000
#define IN_DIM  256
#define HID_DIM 64
#define OUT_DIM 32

#define NBINS      391        // ceil(100000/256), 256 nodes per bin
#define BIN_SHIFT  8
#define BIN_STRIDE 9216       // lambda=8192, +11 sigma headroom
#define BIN_EPB    8192

#define NCHUNK     4
#define CHUNK_DIV  25000      // src chunk = src / 25000 -> 3.2 MB of H1h per chunk
#define AGG_BLOCKS 2048       // exactly 8 blocks/CU co-resident
#define AGG_WAVES  (AGG_BLOCKS * 4)
#define PAIRS      (N_NODES / 2)
#define KMAX       7          // ceil(50000 / 8192)

typedef unsigned int uint;
typedef unsigned char uchar;
typedef unsigned short ushort;

__device__ __forceinline__ float2 h2tof2(uint u) {
    __half2 h = *reinterpret_cast<const __half2*>(&u);
    return __half22float2(h);
}
__device__ __forceinline__ uint f2toh2(float a, float b) {
    __half2 h = __floats2half2_rn(a, b);
    return *reinterpret_cast<const uint*>(&h);
}
__device__ __forceinline__ ushort f2h(float a) {
    __half h = __float2half_rn(a);
    return *reinterpret_cast<const ushort*>(&h);
}
// acc = fma(w, (float)fp16_lo/hi(v), acc) — exact cvt, bit-identical to cvt+fmaf.
__device__ __forceinline__ void fma_mix_lo(float& acc, float w, uint v) {
    asm("v_fma_mix_f32 %0, %1, %2, %0 op_sel:[0,0,0] op_sel_hi:[0,1,0]"
        : "+v"(acc) : "v"(w), "v"(v));
}
__device__ __forceinline__ void fma_mix_hi(float& acc, float w, uint v) {
    asm("v_fma_mix_f32 %0, %1, %2, %0 op_sel:[0,1,0] op_sel_hi:[0,1,0]"
        : "+v"(acc) : "v"(w), "v"(v));
}

// ---------------- pass 1: bin edges by dst>>8 (packed uint), inline last-block scan ----------------
__global__ __launch_bounds__(512)
void k_bin(const int* __restrict__ ei, int* __restrict__ bin_cursor,
           uint* __restrict__ binned, int* __restrict__ bin_base,
           int* __restrict__ rowptr2) {
    __shared__ int   lcount[NBINS];
    __shared__ int   lstart[NBINS];
    __shared__ int   lplace[NBINS];
    __shared__ int   gbase[NBINS];
    __shared__ int   sc[512];
    __shared__ uint  stage[BIN_EPB];    // 32 KB
    __shared__ uchar binid[BIN_EPB];    //  8 KB

    const int tid  = threadIdx.x;
    const int bid  = blockIdx.x;
    int*      done = bin_cursor + NBINS;   // zeroed by memset

    const int e0   = bid * BIN_EPB;
    const int nval = min(BIN_EPB, N_EDGES - e0);

    for (int i = tid; i < NBINS; i += 512) lcount[i] = 0;
    __syncthreads();

    // count pass: batched 4-deep
    #pragma unroll
    for (int k = 0; k < BIN_EPB / 512; k += 4) {
        int d4[4];
        #pragma unroll
        for (int u = 0; u < 4; ++u) {
            int e = e0 + (k + u) * 512 + tid;
            d4[u] = (e < N_EDGES) ? ei[N_EDGES + e] : -1;
        }
        #pragma unroll
        for (int u = 0; u < 4; ++u)
            if (d4[u] >= 0) atomicAdd(&lcount[d4[u] >> BIN_SHIFT], 1);
    }
    __syncthreads();

    int v = (tid < NBINS) ? lcount[tid] : 0;
    sc[tid] = v; __syncthreads();
    for (int off = 1; off < 512; off <<= 1) {
        int x = sc[tid];
        if (tid >= off) x += sc[tid - off];
        __syncthreads(); sc[tid] = x; __syncthreads();
    }
    if (tid < NBINS) {
        int excl = sc[tid] - v;
        lstart[tid] = excl;
        lplace[tid] = excl;
        gbase[tid]  = atomicAdd(&bin_cursor[tid], v);
    }
    __syncthreads();

    // stage pass: batched 4-deep
    #pragma unroll
    for (int k = 0; k < BIN_EPB / 512; k += 4) {
        int s4[4], d4[4];
        #pragma unroll
        for (int u = 0; u < 4; ++u) {
            int e = e0 + (k + u) * 512 + tid;
            bool ok = (e < N_EDGES);
            s4[u] = ok ? ei[e] : -1;
            d4[u] = ok ? ei[N_EDGES + e] : 0;
        }
        #pragma unroll
        for (int u = 0; u < 4; ++u) {
            if (s4[u] >= 0) {
                int b = d4[u] >> BIN_SHIFT;
                int p = atomicAdd(&lplace[b], 1);
                stage[p] = (uint)s4[u] | ((uint)(d4[u] & 255) << 17)
                         | ((uint)(b >> 8) << 25);
                binid[p] = (uchar)(b & 255);
            }
        }
    }
    __syncthreads();

    for (int i = tid; i < nval; i += 512) {
        uint ed = stage[i];
        int  b  = (int)binid[i] | (int)((ed >> 25) & 1u) << 8;
        int  gix = gbase[b] + (i - lstart[b]);
        if (gix < BIN_STRIDE)
            binned[(size_t)b * BIN_STRIDE + gix] = ed;
    }
    __syncthreads();

    // ---- last-block inline binscan ----
    if (tid == 0) {
        __threadfence();
        lcount[0] = (atomicAdd(done, 1) == gridDim.x - 1) ? 1 : 0;
    }
    __syncthreads();
    if (lcount[0]) {
        int t = tid;
        int vv = 0;
        if (t < NBINS) vv = min(atomicAdd(&bin_cursor[t], 0), BIN_STRIDE);
        sc[t] = vv; __syncthreads();
        for (int off = 1; off < 512; off <<= 1) {
            int x = sc[t];
            if (t >= off) x += sc[t - off];
            __syncthreads(); sc[t] = x; __syncthreads();
        }
        if (t < NBINS)      bin_base[t] = sc[t] - vv;
        if (t == NBINS - 1) rowptr2[NCHUNK * N_NODES] = sc[t];
    }
}

// ---------------- pass 2: per-bin counting sort by (node, src-chunk) -> CSR ----------------
// 1024 keys: key = (dst&255)*4 + chunk(src). rowptr2[4*node + chunk].
__global__ __launch_bounds__(512)
void k_csr(const uint* __restrict__ binned, const int* __restrict__ bin_cursor,
           const int* __restrict__ bin_base, int* __restrict__ rowptr2,
           float* __restrict__ dn, int* __restrict__ csr) {
    __shared__ int lcnt[1024];
    __shared__ int lpl[1024];
    __shared__ int sc2[512];
    __shared__ int csr_s[BIN_STRIDE];   // 36.9 KB

    const int tid   = threadIdx.x;
    const int b     = blockIdx.x;
    const int n0    = b << BIN_SHIFT;
    const int cnt   = min(bin_cursor[b], BIN_STRIDE);
    const int ebase = bin_base[b];
    const uint* bb  = binned + (size_t)b * BIN_STRIDE;

    lcnt[tid] = 0; lcnt[tid + 512] = 0;
    __syncthreads();

    // count pass, 4-deep batched loads
    for (int i0 = tid; i0 < cnt; i0 += 2048) {
        uint e4[4]; int ok[4];
        #pragma unroll
        for (int u = 0; u < 4; ++u) {
            int i = i0 + u * 512;
            ok[u] = (i < cnt);
            e4[u] = bb[ok[u] ? i : 0];
        }
        #pragma unroll
        for (int u = 0; u < 4; ++u) {
            if (ok[u]) {
                int key = (int)((e4[u] >> 17) & 255u) * NCHUNK
                        + (int)(e4[u] & 0x1FFFFu) / CHUNK_DIV;
                atomicAdd(&lcnt[key], 1);
            }
        }
    }
    __syncthreads();

    // dn from per-node totals (lcnt intact)
    if (tid < 256) {
        int n = n0 + tid;
        if (n < N_NODES) {
            int vt = lcnt[4 * tid] + lcnt[4 * tid + 1]
                   + lcnt[4 * tid + 2] + lcnt[4 * tid + 3];
            dn[n] = rsqrtf((float)vt + 1.0f);   // +1 self-loop
        }
    }

    // 1024-entry exclusive scan, 2 keys per thread
    int a0 = lcnt[2 * tid], a1 = lcnt[2 * tid + 1];
    int s  = a0 + a1;
    sc2[tid] = s; __syncthreads();
    for (int off = 1; off < 512; off <<= 1) {
        int x = sc2[tid];
        if (tid >= off) x += sc2[tid - off];
        __syncthreads(); sc2[tid] = x; __syncthreads();
    }
    int pair_excl = sc2[tid] - s;
    lpl[2 * tid]     = pair_excl;
    lpl[2 * tid + 1] = pair_excl + a0;
    {
        int key0 = 2 * tid;
        int nl0  = key0 >> 2;
        if (n0 + nl0 < N_NODES) {
            rowptr2[4 * n0 + key0]     = ebase + pair_excl;
            rowptr2[4 * n0 + key0 + 1] = ebase + pair_excl + a0;
        }
    }
    __syncthreads();

    // placement pass, 4-deep batched loads
    for (int i0 = tid; i0 < cnt; i0 += 2048) {
        uint e4[4]; int ok[4];
        #pragma unroll
        for (int u = 0; u < 4; ++u) {
            int i = i0 + u * 512;
            ok[u] = (i < cnt);
            e4[u] = bb[ok[u] ? i : 0];
        }
        #pragma unroll
        for (int u = 0; u < 4; ++u) {
            if (ok[u]) {
                int src = (int)(e4[u] & 0x1FFFFu);
                int key = (int)((e4[u] >> 17) & 255u) * NCHUNK + src / CHUNK_DIV;
                int p = atomicAdd(&lpl[key], 1);
                csr_s[p] = src;
            }
        }
    }
    __syncthreads();
    for (int i = tid; i < cnt; i += 512)
        csr[ebase + i] = csr_s[i];
}

// ---------------- tiled fp32 GEMM (r16 row-major, known-good): fp16 output ----------------
template<int KD, int NC>
__global__ __launch_bounds__(32 * (NC / 8))
void k_gemm_h(const float* __restrict__ X, const float* __restrict__ W,
              uint* __restrict__ Yh, int M) {
    constexpr int TC = NC / 8;
    constexpr int THREADS = 32 * TC;
    constexpr int KC = 32;
    __shared__ float Xs[128][33];
    __shared__ float Ws[KC][NC];

    const int tid  = threadIdx.x;
    const int tr   = tid / TC;
    const int tc   = tid % TC;
    const int row0 = blockIdx.x * 128;

    float acc[4][8];
    #pragma unroll
    for (int i = 0; i < 4; ++i)
        #pragma unroll
        for (int j = 0; j < 8; ++j) acc[i][j] = 0.f;

    for (int kc = 0; kc < KD; kc += KC) {
        #pragma unroll
        for (int i = tid; i < 128 * (KC / 4); i += THREADS) {
            int r  = i / (KC / 4);
            int k4 = (i % (KC / 4)) * 4;
            float4 v = make_float4(0.f, 0.f, 0.f, 0.f);
            int gr = row0 + r;
            if (gr < M)
                v = *reinterpret_cast<const float4*>(&X[(size_t)gr * KD + kc + k4]);
            Xs[r][k4 + 0] = v.x; Xs[r][k4 + 1] = v.y;
            Xs[r][k4 + 2] = v.z; Xs[r][k4 + 3] = v.w;
        }
        #pragma unroll
        for (int i = tid; i < KC * (NC / 4); i += THREADS) {
            int kk = i / (NC / 4);
            int c4 = (i % (NC / 4)) * 4;
            *reinterpret_cast<float4*>(&Ws[kk][c4]) =
                *reinterpret_cast<const float4*>(&W[(size_t)(kc + kk) * NC + c4]);
        }
        __syncthreads();

        #pragma unroll
        for (int kk = 0; kk < KC; ++kk) {
            float xv[4];
            #pragma unroll
            for (int i = 0; i < 4; ++i) xv[i] = Xs[tr * 4 + i][kk];
            float4 w0 = *reinterpret_cast<const float4*>(&Ws[kk][tc * 8]);
            float4 w1 = *reinterpret_cast<const float4*>(&Ws[kk][tc * 8 + 4]);
            float wv[8] = {w0.x, w0.y, w0.z, w0.w, w1.x, w1.y, w1.z, w1.w};
            #pragma unroll
            for (int i = 0; i < 4; ++i)
                #pragma unroll
                for (int j = 0; j < 8; ++j)
                    acc[i][j] = fmaf(xv[i], wv[j], acc[i][j]);
        }
        __syncthreads();
    }

    #pragma unroll
    for (int i = 0; i < 4; ++i) {
        int gr = row0 + tr * 4 + i;
        if (gr < M) {
            uint4 o;
            o.x = f2toh2(acc[i][0], acc[i][1]);
            o.y = f2toh2(acc[i][2], acc[i][3]);
            o.z = f2toh2(acc[i][4], acc[i][5]);
            o.w = f2toh2(acc[i][6], acc[i][7]);
            *reinterpret_cast<uint4*>(&Yh[(size_t)gr * (NC / 2) + tc * 4]) = o;
        }
    }
}

// ---------------- agg1: phase-coherent chunked gather + fused GEMM2 -> H2 ----------------
// Persistent-style grid (2048 blocks = 8/CU co-resident). Each wave owns KMAX
// node-pairs (acc in registers, statically unrolled); ALL waves sweep src-chunks
// in the same order -> during phase c gathers target a 3.2 MB slice (L2-fits).
// Per-feature chain: single accumulator, self first, then edges in
// (chunk-ascending, within-chunk CSR) order; idle slots exact fma(0,.).
__global__ __launch_bounds__(256)
void k_agg1(const uint* __restrict__ H1h, const int* __restrict__ rowptr2,
            const int* __restrict__ csr, const float* __restrict__ dn,
            const float* __restrict__ b1, const float* __restrict__ W2,
            ushort* __restrict__ H2h) {
    __shared__ float W2s[HID_DIM * OUT_DIM];   // 8 KB
    for (int i = threadIdx.x; i < HID_DIM * OUT_DIM; i += 256) W2s[i] = W2[i];
    __syncthreads();

    const int wave0 = (blockIdx.x * 256 + threadIdx.x) >> 6;   // 0..AGG_WAVES-1
    const int lane  = threadIdx.x & 63;
    const int half  = lane >> 5;
    const int hb    = half << 5;
    const int l     = lane & 31;

    float2 acc[KMAX];
    // init with self-term (order: self first)
    #pragma unroll
    for (int k = 0; k < KMAX; ++k) {
        acc[k] = make_float2(0.f, 0.f);
        int pair = wave0 + k * AGG_WAVES;
        if (pair < PAIRS) {
            int n = 2 * pair + half;
            float dnn = dn[n];
            float2 s2 = h2tof2(H1h[(size_t)n * 32 + l]);
            acc[k].x = dnn * s2.x;
            acc[k].y = dnn * s2.y;
        }
    }

    // chunk phases
    for (int c = 0; c < NCHUNK; ++c) {
        #pragma unroll
        for (int k = 0; k < KMAX; ++k) {
            int pair = wave0 + k * AGG_WAVES;
            if (pair >= PAIRS) continue;            // wave-uniform
            int n = 2 * pair + half;
            int rp = (l < 2) ? rowptr2[4 * n + c + l] : 0;
            int base = __shfl(rp, hb + 0);
            int cnt  = __shfl(rp, hb + 1) - base;
            int cnt2 = max(cnt, __shfl_xor(cnt, 32));
            for (int b0 = 0; b0 < cnt2; b0 += 32) {
                int m_own = min(32, cnt - b0);
                int m_max = min(32, cnt2 - b0);
                int s = 0; float dsv = 0.f;
                if (l < m_own) { s = csr[base + b0 + l]; dsv = dn[s]; }
                for (int j0 = 0; j0 < m_max; j0 += 8) {
                    uint v[8]; float w[8];
                    #pragma unroll
                    for (int i = 0; i < 8; ++i) {
                        int j  = j0 + i;
                        int sj = __shfl(s, hb + j);
                        w[i] = __shfl(dsv, hb + j);
                        v[i] = H1h[(size_t)sj * 32 + l];
                    }
                    #pragma unroll
                    for (int i = 0; i < 8; ++i) {
                        fma_mix_lo(acc[k].x, w[i], v[i]);
                        fma_mix_hi(acc[k].y, w[i], v[i]);
                    }
                }
            }
        }
    }

    // epilogue per pair: bias+relu + fused GEMM2 (r5 association)
    const int c2 = lane & 31, hh = lane >> 5;
    #pragma unroll
    for (int k = 0; k < KMAX; ++k) {
        int pair = wave0 + k * AGG_WAVES;
        if (pair >= PAIRS) continue;
        int n = 2 * pair + half;
        float dnn = dn[n];
        float2 b1q = *reinterpret_cast<const float2*>(b1 + 2 * l);
        float2 o;
        o.x = fmaxf(b1q.x + dnn * acc[k].x, 0.f);
        o.y = fmaxf(b1q.y + dnn * acc[k].y, 0.f);

        #pragma unroll
        for (int nodesel = 0; nodesel < 2; ++nodesel) {
            const int nb = nodesel << 5;
            float acc2 = 0.f;
            #pragma unroll
            for (int fi = 0; fi < 32; ++fi) {
                int f = hh * 32 + fi;
                float vv = (f & 1) ? __shfl(o.y, nb + (f >> 1))
                                   : __shfl(o.x, nb + (f >> 1));
                acc2 = fmaf(vv, W2s[f * OUT_DIM + c2], acc2);
            }
            acc2 += __shfl_xor(acc2, 32);
            if (hh == 0) H2h[(size_t)(2 * pair + nodesel) * 32 + c2] = f2h(acc2);
        }
    }
}

// ---------------- agg2 (+bias) fused with MLP head ----------------
// TWO nodes per wave (r12/r16 structure, passing), fp16x2 gathers + fma_mix.
// Full-node segment = rowptr2[4n] .. rowptr2[4(n+1)] (chunks contiguous).
__global__ __launch_bounds__(256)
void k_agg2m(const uint* __restrict__ H2h, const int* __restrict__ rowptr2,
             const int* __restrict__ csr, const float* __restrict__ dn,
             const float* __restrict__ b2, const float* __restrict__ Wp1,
             const float* __restrict__ bp1, const float* __restrict__ Wp2,
             const float* __restrict__ bp2, float* __restrict__ out_h,
             float* __restrict__ out_w) {
    __shared__ float Wp1s[OUT_DIM * HID_DIM];  // 8 KB
    __shared__ float Wp2s[HID_DIM];
    __shared__ float bp1s[HID_DIM];
    for (int i = threadIdx.x; i < OUT_DIM * HID_DIM; i += 256) Wp1s[i] = Wp1[i];
    if (threadIdx.x < HID_DIM) {
        Wp2s[threadIdx.x] = Wp2[threadIdx.x];
        bp1s[threadIdx.x] = bp1[threadIdx.x];
    }
    __syncthreads();

    int wid  = (blockIdx.x * blockDim.x + threadIdx.x) >> 6;
    int lane = threadIdx.x & 63;
    if (wid >= N_NODES / 2) return;
    const int nd  = lane >> 5;
    const int nb0 = nd << 5;
    const int l32 = lane & 31;
    const int l   = lane & 15;
    const int h2  = (lane >> 4) & 1;
    const int n   = 2 * wid + nd;

    int rp = (lane < 3) ? rowptr2[8 * wid + 4 * lane] : 0;
    int base = __shfl(rp, nd);
    int cnt  = __shfl(rp, nd + 1) - base;
    const float dnn = dn[n];

    float2 self2 = h2tof2(H2h[(size_t)n * 16 + l]);
    float2 acc;
    acc.x = (h2 == 0) ? dnn * self2.x : 0.f;
    acc.y = (h2 == 0) ? dnn * self2.y : 0.f;

    const int cnt2 = max(cnt, __shfl_xor(cnt, 32));
    for (int b0 = 0; b0 < cnt2; b0 += 32) {
        int m_own = min(32, cnt - b0);
        int m_max = min(32, cnt2 - b0);
        int s = 0; float dsv = 0.f;
        if (l32 < m_own) { s = csr[base + b0 + l32]; dsv = dn[s]; }
        for (int j0 = h2; j0 < m_max; j0 += 16) {
            uint v[8]; float w[8];
            #pragma unroll
            for (int i = 0; i < 8; ++i) {
                int j  = j0 + 2 * i;              // <= j0+14 <= 31
                int sj = __shfl(s, nb0 + j);
                w[i] = __shfl(dsv, nb0 + j);      // 0 when j >= m_own
                v[i] = H2h[(size_t)sj * 16 + l];
            }
            #pragma unroll
            for (int i = 0; i < 8; ++i) {
                fma_mix_lo(acc.x, w[i], v[i]);
                fma_mix_hi(acc.y, w[i], v[i]);
            }
        }
    }
    acc.x += __shfl_xor(acc.x, 16);               // even + odd (r5 association)
    acc.y += __shfl_xor(acc.y, 16);
    float2 b2q = *reinterpret_cast<const float2*>(b2 + 2 * l);
    float2 hv;
    hv.x = b2q.x + dnn * acc.x;
    hv.y = b2q.y + dnn * acc.y;
    if (h2 == 0)
        *reinterpret_cast<float2*>(out_h + (size_t)n * OUT_DIM + 2 * l) = hv;

    // MLP head per node: p[j]=relu(bp1[j]+sum_ff h_ff Wp1[ff][j])
    #pragma unroll
    for (int nodesel = 0; nodesel < 2; ++nodesel) {
        const int nb = nodesel << 5;
        float p = bp1s[lane];
        #pragma unroll
        for (int ff = 0; ff < OUT_DIM; ++ff) {
            float hf = (ff & 1) ? __shfl(hv.y, nb + (ff >> 1))
                                : __shfl(hv.x, nb + (ff >> 1));
            p = fmaf(hf, Wp1s[ff * HID_DIM + lane], p);
        }
        p = fmaxf(p, 0.f);
        float z = p * Wp2s[lane];
        #pragma unroll
        for (int off = 32; off; off >>= 1) z += __shfl_xor(z, off);
        if (lane == 0)
            out_w[2 * wid + nodesel] = 1.f / (1.f + __expf(-(z + bp2[0])));
    }
}

// ---------------- launcher ----------------
extern "C" void kernel_launch(void* const* d_in, const int* in_sizes, int n_in,
                              void* d_out, int out_size, void* d_ws, size_t ws_size,
                              hipStream_t stream) {
    const float* x   = (const float*)d_in[0];
    const int*   ei  = (const int*)d_in[1];
    const float* W1  = (const float*)d_in[2];
    const float* b1  = (const float*)d_in[3];
    const float* W2  = (const float*)d_in[4];
    const float* b2  = (const float*)d_in[5];
    const float* Wp1 = (const float*)d_in[6];
    const float* bp1 = (const float*)d_in[7];
    const float* Wp2 = (const float*)d_in[8];
    const float* bp2 = (const float*)d_in[9];
    float* out = (float*)d_out;

    char* ws = (char*)d_ws;
    // binned = NBINS*BIN_STRIDE*4 = 14,413,824 B (slot count, not edge count!)
    // rowptr2 = (4*N_NODES+1)*4 = 1,600,004 B
    int*    bin_cursor = (int*)   (ws + 0);          //  1,568 B (incl. done ctr)
    int*    bin_base   = (int*)   (ws + 2048);       //  1,564 B
    int*    rowptr2    = (int*)   (ws + 4096);       //  1,600,004 -> ends 1,604,100
    float*  dn         = (float*) (ws + 1604608);    //  400,000 -> ends 2,004,608
    int*    csr        = (int*)   (ws + 2004608);    //  12,800,000 -> ends 14,804,608
    uint*   binned     = (uint*)  (ws + 14804608);   //  14,413,824 -> ends 29,218,432
    uint*   H1h        = (uint*)  (ws + 29218432);   //  12,800,000 -> ends 42,018,432
    ushort* H2h        = (ushort*)(ws + 42018432);   //   6,400,000 -> ends 48,418,432

    hipMemsetAsync(bin_cursor, 0, (NBINS + 1) * sizeof(int), stream);

    k_bin<<<(N_EDGES + BIN_EPB - 1) / BIN_EPB, 512, 0, stream>>>(ei, bin_cursor, binned,
                                                                 bin_base, rowptr2);
    k_csr<<<NBINS, 512, 0, stream>>>(binned, bin_cursor, bin_base, rowptr2, dn, csr);
    k_gemm_h<IN_DIM, HID_DIM><<<(N_NODES + 127) / 128, 256, 0, stream>>>(x, W1, H1h, N_NODES);

    k_agg1<<<AGG_BLOCKS, 256, 0, stream>>>(H1h, rowptr2, csr, dn, b1, W2, (ushort*)H2h);
    k_agg2m<<<(N_NODES / 2 + 3) / 4, 256, 0, stream>>>((const uint*)H2h, rowptr2, csr, dn, b2,
                                                       Wp1, bp1, Wp2, bp2,
                                                       out, out + (size_t)N_NODES * OUT_DIM);
}

// Round 19
// 294.793 us; speedup vs baseline: 1.1787x; 1.1787x over previous
//
#include <hip/hip_runtime.h>
#include <hip/hip_fp16.h>
#include <cstdint>
#include <cstddef>

#define N_NODES 100000
#define N_EDGES 3200000
#define IN_DIM  256
#define HID_DIM 64
#define OUT_DIM 32

#define NBINS      391        // ceil(100000/256), 256 nodes per bin
#define BIN_SHIFT  8
#define BIN_STRIDE 9216       // lambda=8192, +11 sigma headroom
#define BIN_EPB    8192

typedef unsigned int uint;
typedef unsigned char uchar;
typedef unsigned short ushort;

__device__ __forceinline__ float2 h2tof2(uint u) {
    __half2 h = *reinterpret_cast<const __half2*>(&u);
    return __half22float2(h);
}
__device__ __forceinline__ uint f2toh2(float a, float b) {
    __half2 h = __floats2half2_rn(a, b);
    return *reinterpret_cast<const uint*>(&h);
}
__device__ __forceinline__ ushort f2h(float a) {
    __half h = __float2half_rn(a);
    return *reinterpret_cast<const ushort*>(&h);
}
// acc = fma(w, (float)fp16_lo/hi(v), acc) — exact cvt, bit-identical to cvt+fmaf.
__device__ __forceinline__ void fma_mix_lo(float& acc, float w, uint v) {
    asm("v_fma_mix_f32 %0, %1, %2, %0 op_sel:[0,0,0] op_sel_hi:[0,1,0]"
        : "+v"(acc) : "v"(w), "v"(v));
}
__device__ __forceinline__ void fma_mix_hi(float& acc, float w, uint v) {
    asm("v_fma_mix_f32 %0, %1, %2, %0 op_sel:[0,1,0] op_sel_hi:[0,1,0]"
        : "+v"(acc) : "v"(w), "v"(v));
}

// ---------------- pass 1: bin edges by dst>>8 (packed uint), inline last-block scan ----------------
// Global-load loops batched 4-deep (latency fix; loads issued together).
__global__ __launch_bounds__(512)
void k_bin(const int* __restrict__ ei, int* __restrict__ bin_cursor,
           uint* __restrict__ binned, int* __restrict__ bin_base,
           int* __restrict__ rowptr) {
    __shared__ int   lcount[NBINS];
    __shared__ int   lstart[NBINS];
    __shared__ int   lplace[NBINS];
    __shared__ int   gbase[NBINS];
    __shared__ int   sc[512];
    __shared__ uint  stage[BIN_EPB];    // 32 KB
    __shared__ uchar binid[BIN_EPB];    //  8 KB

    const int tid  = threadIdx.x;
    const int bid  = blockIdx.x;
    int*      done = bin_cursor + NBINS;   // zeroed by memset

    const int e0   = bid * BIN_EPB;
    const int nval = min(BIN_EPB, N_EDGES - e0);

    for (int i = tid; i < NBINS; i += 512) lcount[i] = 0;
    __syncthreads();

    // count pass: 16 edges/thread, batched 4-deep
    #pragma unroll
    for (int k = 0; k < BIN_EPB / 512; k += 4) {
        int d4[4];
        #pragma unroll
        for (int u = 0; u < 4; ++u) {
            int e = e0 + (k + u) * 512 + tid;
            d4[u] = (e < N_EDGES) ? ei[N_EDGES + e] : -1;
        }
        #pragma unroll
        for (int u = 0; u < 4; ++u)
            if (d4[u] >= 0) atomicAdd(&lcount[d4[u] >> BIN_SHIFT], 1);
    }
    __syncthreads();

    int v = (tid < NBINS) ? lcount[tid] : 0;
    sc[tid] = v; __syncthreads();
    for (int off = 1; off < 512; off <<= 1) {
        int x = sc[tid];
        if (tid >= off) x += sc[tid - off];
        __syncthreads(); sc[tid] = x; __syncthreads();
    }
    if (tid < NBINS) {
        int excl = sc[tid] - v;
        lstart[tid] = excl;
        lplace[tid] = excl;
        gbase[tid]  = atomicAdd(&bin_cursor[tid], v);
    }
    __syncthreads();

    // stage pass: batched 4-deep loads of (s,d)
    #pragma unroll
    for (int k = 0; k < BIN_EPB / 512; k += 4) {
        int s4[4], d4[4];
        #pragma unroll
        for (int u = 0; u < 4; ++u) {
            int e = e0 + (k + u) * 512 + tid;
            bool ok = (e < N_EDGES);
            s4[u] = ok ? ei[e] : -1;
            d4[u] = ok ? ei[N_EDGES + e] : 0;
        }
        #pragma unroll
        for (int u = 0; u < 4; ++u) {
            if (s4[u] >= 0) {
                int b = d4[u] >> BIN_SHIFT;
                int p = atomicAdd(&lplace[b], 1);
                stage[p] = (uint)s4[u] | ((uint)(d4[u] & 255) << 17)
                         | ((uint)(b >> 8) << 25);
                binid[p] = (uchar)(b & 255);
            }
        }
    }
    __syncthreads();

    for (int i = tid; i < nval; i += 512) {
        uint ed = stage[i];
        int  b  = (int)binid[i] | (int)((ed >> 25) & 1u) << 8;
        int  gix = gbase[b] + (i - lstart[b]);
        if (gix < BIN_STRIDE)
            binned[(size_t)b * BIN_STRIDE + gix] = ed;
    }
    __syncthreads();

    // ---- last-block inline binscan ----
    if (tid == 0) {
        __threadfence();
        lcount[0] = (atomicAdd(done, 1) == gridDim.x - 1) ? 1 : 0;
    }
    __syncthreads();
    if (lcount[0]) {
        int t = tid;
        int vv = 0;
        if (t < NBINS) vv = min(atomicAdd(&bin_cursor[t], 0), BIN_STRIDE);
        sc[t] = vv; __syncthreads();
        for (int off = 1; off < 512; off <<= 1) {
            int x = sc[t];
            if (t >= off) x += sc[t - off];
            __syncthreads(); sc[t] = x; __syncthreads();
        }
        if (t < NBINS)      bin_base[t] = sc[t] - vv;
        if (t == NBINS - 1) rowptr[N_NODES] = sc[t];
    }
}

// ---------------- pass 2: per-bin LDS counting sort -> CSR (+dn), 512 thr, batched ----------------
__global__ __launch_bounds__(512)
void k_csr(const uint* __restrict__ binned, const int* __restrict__ bin_cursor,
           const int* __restrict__ bin_base, int* __restrict__ rowptr,
           float* __restrict__ dn, int* __restrict__ csr) {
    __shared__ int lcnt[256];
    __shared__ int lpl[256];
    __shared__ int sc[256];
    __shared__ int csr_s[BIN_STRIDE];   // 36.9 KB

    const int tid   = threadIdx.x;
    const int b     = blockIdx.x;
    const int n0    = b << BIN_SHIFT;
    const int cnt   = min(bin_cursor[b], BIN_STRIDE);
    const int ebase = bin_base[b];
    const uint* bb  = binned + (size_t)b * BIN_STRIDE;

    if (tid < 256) lcnt[tid] = 0;
    __syncthreads();

    // count pass, 4-deep batched loads
    for (int i0 = tid; i0 < cnt; i0 += 2048) {
        uint e4[4]; int ok[4];
        #pragma unroll
        for (int u = 0; u < 4; ++u) {
            int i = i0 + u * 512;
            ok[u] = (i < cnt);
            e4[u] = bb[ok[u] ? i : 0];
        }
        #pragma unroll
        for (int u = 0; u < 4; ++u)
            if (ok[u]) atomicAdd(&lcnt[(e4[u] >> 17) & 255u], 1);
    }
    __syncthreads();

    int v = 0;
    if (tid < 256) { v = lcnt[tid]; sc[tid] = v; }
    __syncthreads();
    for (int off = 1; off < 256; off <<= 1) {
        int x = 0;
        if (tid < 256) { x = sc[tid]; if (tid >= off) x += sc[tid - off]; }
        __syncthreads();
        if (tid < 256) sc[tid] = x;
        __syncthreads();
    }
    if (tid < 256) {
        int excl = sc[tid] - v;
        lpl[tid] = excl;
        int n = n0 + tid;
        if (n < N_NODES) {
            rowptr[n] = ebase + excl;
            dn[n]     = rsqrtf((float)v + 1.0f);   // +1 self-loop
        }
    }
    __syncthreads();

    // placement pass, 4-deep batched loads
    for (int i0 = tid; i0 < cnt; i0 += 2048) {
        uint e4[4]; int ok[4];
        #pragma unroll
        for (int u = 0; u < 4; ++u) {
            int i = i0 + u * 512;
            ok[u] = (i < cnt);
            e4[u] = bb[ok[u] ? i : 0];
        }
        #pragma unroll
        for (int u = 0; u < 4; ++u) {
            if (ok[u]) {
                int p = atomicAdd(&lpl[(e4[u] >> 17) & 255u], 1);
                csr_s[p] = (int)(e4[u] & 0x1FFFFu);
            }
        }
    }
    __syncthreads();
    for (int i = tid; i < cnt; i += 512)
        csr[ebase + i] = csr_s[i];
}

// ---------------- tiled fp32 GEMM: Y[M,NC] = X[M,KD] @ W[KD,NC], fp16 output ----------------
template<int KD, int NC>
__global__ __launch_bounds__(32 * (NC / 8))
void k_gemm_h(const float* __restrict__ X, const float* __restrict__ W,
              uint* __restrict__ Yh, int M) {
    constexpr int TC = NC / 8;
    constexpr int THREADS = 32 * TC;
    constexpr int KC = 32;
    __shared__ float Xs[128][33];
    __shared__ float Ws[KC][NC];

    const int tid  = threadIdx.x;
    const int tr   = tid / TC;
    const int tc   = tid % TC;
    const int row0 = blockIdx.x * 128;

    float acc[4][8];
    #pragma unroll
    for (int i = 0; i < 4; ++i)
        #pragma unroll
        for (int j = 0; j < 8; ++j) acc[i][j] = 0.f;

    for (int kc = 0; kc < KD; kc += KC) {
        #pragma unroll
        for (int i = tid; i < 128 * (KC / 4); i += THREADS) {
            int r  = i / (KC / 4);
            int k4 = (i % (KC / 4)) * 4;
            float4 v = make_float4(0.f, 0.f, 0.f, 0.f);
            int gr = row0 + r;
            if (gr < M)
                v = *reinterpret_cast<const float4*>(&X[(size_t)gr * KD + kc + k4]);
            Xs[r][k4 + 0] = v.x; Xs[r][k4 + 1] = v.y;
            Xs[r][k4 + 2] = v.z; Xs[r][k4 + 3] = v.w;
        }
        #pragma unroll
        for (int i = tid; i < KC * (NC / 4); i += THREADS) {
            int kk = i / (NC / 4);
            int c4 = (i % (NC / 4)) * 4;
            *reinterpret_cast<float4*>(&Ws[kk][c4]) =
                *reinterpret_cast<const float4*>(&W[(size_t)(kc + kk) * NC + c4]);
        }
        __syncthreads();

        #pragma unroll
        for (int kk = 0; kk < KC; ++kk) {
            float xv[4];
            #pragma unroll
            for (int i = 0; i < 4; ++i) xv[i] = Xs[tr * 4 + i][kk];
            float4 w0 = *reinterpret_cast<const float4*>(&Ws[kk][tc * 8]);
            float4 w1 = *reinterpret_cast<const float4*>(&Ws[kk][tc * 8 + 4]);
            float wv[8] = {w0.x, w0.y, w0.z, w0.w, w1.x, w1.y, w1.z, w1.w};
            #pragma unroll
            for (int i = 0; i < 4; ++i)
                #pragma unroll
                for (int j = 0; j < 8; ++j)
                    acc[i][j] = fmaf(xv[i], wv[j], acc[i][j]);
        }
        __syncthreads();
    }

    #pragma unroll
    for (int i = 0; i < 4; ++i) {
        int gr = row0 + tr * 4 + i;
        if (gr < M) {
            uint4 o;
            o.x = f2toh2(acc[i][0], acc[i][1]);
            o.y = f2toh2(acc[i][2], acc[i][3]);
            o.z = f2toh2(acc[i][4], acc[i][5]);
            o.w = f2toh2(acc[i][6], acc[i][7]);
            *reinterpret_cast<uint4*>(&Yh[(size_t)gr * (NC / 2) + tc * 4]) = o;
        }
    }
}

// ---------------- agg1 (+bias+relu) fused with GEMM2 -> H2 (fp16) ----------------
// TWO nodes per wave (r16 structure); fp16x2 gathers; fp32 accum via v_fma_mix.
// Load batch widened 8 -> 16 (16 gathers in flight/wave). FP chain bit-identical:
// fmas still applied in ascending j order; idle slots exact fma(0,.).
__global__ __launch_bounds__(256)
void k_agg1(const uint* __restrict__ H1h, const int* __restrict__ rowptr,
            const int* __restrict__ csr, const float* __restrict__ dn,
            const float* __restrict__ b1, const float* __restrict__ W2,
            ushort* __restrict__ H2h) {
    __shared__ float W2s[HID_DIM * OUT_DIM];   // 8 KB
    for (int i = threadIdx.x; i < HID_DIM * OUT_DIM; i += 256) W2s[i] = W2[i];
    __syncthreads();

    int wid  = (blockIdx.x * blockDim.x + threadIdx.x) >> 6;
    int lane = threadIdx.x & 63;
    if (wid >= N_NODES / 2) return;
    const int half = lane >> 5;
    const int hb   = half << 5;
    const int l    = lane & 31;
    const int n    = 2 * wid + half;

    int rp = (l < 2) ? rowptr[n + l] : 0;
    int base = __shfl(rp, hb + 0);
    int cnt  = __shfl(rp, hb + 1) - base;
    const float dnn = dn[n];

    float2 self2 = h2tof2(H1h[(size_t)n * 32 + l]);
    float2 acc;
    acc.x = dnn * self2.x;
    acc.y = dnn * self2.y;

    const int cnt2 = max(cnt, __shfl_xor(cnt, 32));
    for (int b0 = 0; b0 < cnt2; b0 += 32) {
        int m_own = min(32, cnt - b0);
        int m_max = min(32, cnt2 - b0);
        int s = 0; float dsv = 0.f;
        if (l < m_own) { s = csr[base + b0 + l]; dsv = dn[s]; }
        for (int j0 = 0; j0 < m_max; j0 += 16) {
            uint v[16]; float w[16];
            #pragma unroll
            for (int i = 0; i < 16; ++i) {
                int j  = j0 + i;                  // <= 31
                int sj = __shfl(s, hb + j);
                w[i] = __shfl(dsv, hb + j);       // 0 when j >= m_own
                v[i] = H1h[(size_t)sj * 32 + l];
            }
            #pragma unroll
            for (int i = 0; i < 16; ++i) {
                fma_mix_lo(acc.x, w[i], v[i]);
                fma_mix_hi(acc.y, w[i], v[i]);
            }
        }
    }
    float2 b1q = *reinterpret_cast<const float2*>(b1 + 2 * l);
    float2 o;
    o.x = fmaxf(b1q.x + dnn * acc.x, 0.f);
    o.y = fmaxf(b1q.y + dnn * acc.y, 0.f);

    const int c = lane & 31, hh = lane >> 5;
    #pragma unroll
    for (int nodesel = 0; nodesel < 2; ++nodesel) {
        const int nb = nodesel << 5;
        float acc2 = 0.f;
        #pragma unroll
        for (int fi = 0; fi < 32; ++fi) {
            int f = hh * 32 + fi;
            float vv = (f & 1) ? __shfl(o.y, nb + (f >> 1))
                               : __shfl(o.x, nb + (f >> 1));
            acc2 = fmaf(vv, W2s[f * OUT_DIM + c], acc2);
        }
        acc2 += __shfl_xor(acc2, 32);
        if (hh == 0) H2h[(size_t)(2 * wid + nodesel) * 32 + c] = f2h(acc2);
    }
}

// ---------------- agg2 (+bias) fused with MLP head ----------------
// TWO nodes per wave (r16 structure), fp16x2 gathers + fma_mix. Parity streams
// widened to 16 loads in flight (single j0 pass per 32-block, ascending j).
__global__ __launch_bounds__(256)
void k_agg2m(const uint* __restrict__ H2h, const int* __restrict__ rowptr,
             const int* __restrict__ csr, const float* __restrict__ dn,
             const float* __restrict__ b2, const float* __restrict__ Wp1,
             const float* __restrict__ bp1, const float* __restrict__ Wp2,
             const float* __restrict__ bp2, float* __restrict__ out_h,
             float* __restrict__ out_w) {
    __shared__ float Wp1s[OUT_DIM * HID_DIM];  // 8 KB
    __shared__ float Wp2s[HID_DIM];
    __shared__ float bp1s[HID_DIM];
    for (int i = threadIdx.x; i < OUT_DIM * HID_DIM; i += 256) Wp1s[i] = Wp1[i];
    if (threadIdx.x < HID_DIM) {
        Wp2s[threadIdx.x] = Wp2[threadIdx.x];
        bp1s[threadIdx.x] = bp1[threadIdx.x];
    }
    __syncthreads();

    int wid  = (blockIdx.x * blockDim.x + threadIdx.x) >> 6;
    int lane = threadIdx.x & 63;
    if (wid >= N_NODES / 2) return;
    const int nd  = lane >> 5;
    const int nb0 = nd << 5;
    const int l32 = lane & 31;
    const int l   = lane & 15;
    const int h2  = (lane >> 4) & 1;
    const int n   = 2 * wid + nd;

    int rp = (lane < 3) ? rowptr[2 * wid + lane] : 0;
    int base = __shfl(rp, nd);
    int cnt  = __shfl(rp, nd + 1) - base;
    const float dnn = dn[n];

    float2 self2 = h2tof2(H2h[(size_t)n * 16 + l]);
    float2 acc;
    acc.x = (h2 == 0) ? dnn * self2.x : 0.f;
    acc.y = (h2 == 0) ? dnn * self2.y : 0.f;

    const int cnt2 = max(cnt, __shfl_xor(cnt, 32));
    for (int b0 = 0; b0 < cnt2; b0 += 32) {
        int m_own = min(32, cnt - b0);
        int m_max = min(32, cnt2 - b0);
        int s = 0; float dsv = 0.f;
        if (l32 < m_own) { s = csr[base + b0 + l32]; dsv = dn[s]; }
        // single pass: j = h2, h2+2, ..., h2+30 (16 edges per parity stream)
        if (h2 < m_max) {
            uint v[16]; float w[16];
            #pragma unroll
            for (int i = 0; i < 16; ++i) {
                int j  = h2 + 2 * i;              // <= 31
                int sj = __shfl(s, nb0 + j);
                w[i] = __shfl(dsv, nb0 + j);      // 0 when j >= m_own
                v[i] = H2h[(size_t)sj * 16 + l];
            }
            #pragma unroll
            for (int i = 0; i < 16; ++i) {
                fma_mix_lo(acc.x, w[i], v[i]);
                fma_mix_hi(acc.y, w[i], v[i]);
            }
        }
    }
    acc.x += __shfl_xor(acc.x, 16);               // even + odd (r5 association)
    acc.y += __shfl_xor(acc.y, 16);
    float2 b2q = *reinterpret_cast<const float2*>(b2 + 2 * l);
    float2 hv;
    hv.x = b2q.x + dnn * acc.x;
    hv.y = b2q.y + dnn * acc.y;
    if (h2 == 0)
        *reinterpret_cast<float2*>(out_h + (size_t)n * OUT_DIM + 2 * l) = hv;

    // MLP head per node: p[j]=relu(bp1[j]+sum_ff h_ff Wp1[ff][j])
    #pragma unroll
    for (int nodesel = 0; nodesel < 2; ++nodesel) {
        const int nb = nodesel << 5;
        float p = bp1s[lane];
        #pragma unroll
        for (int ff = 0; ff < OUT_DIM; ++ff) {
            float hf = (ff & 1) ? __shfl(hv.y, nb + (ff >> 1))
                                : __shfl(hv.x, nb + (ff >> 1));
            p = fmaf(hf, Wp1s[ff * HID_DIM + lane], p);
        }
        p = fmaxf(p, 0.f);
        float z = p * Wp2s[lane];
        #pragma unroll
        for (int off = 32; off; off >>= 1) z += __shfl_xor(z, off);
        if (lane == 0)
            out_w[2 * wid + nodesel] = 1.f / (1.f + __expf(-(z + bp2[0])));
    }
}

// ---------------- launcher ----------------
extern "C" void kernel_launch(void* const* d_in, const int* in_sizes, int n_in,
                              void* d_out, int out_size, void* d_ws, size_t ws_size,
                              hipStream_t stream) {
    const float* x   = (const float*)d_in[0];
    const int*   ei  = (const int*)d_in[1];
    const float* W1  = (const float*)d_in[2];
    const float* b1  = (const float*)d_in[3];
    const float* W2  = (const float*)d_in[4];
    const float* b2  = (const float*)d_in[5];
    const float* Wp1 = (const float*)d_in[6];
    const float* bp1 = (const float*)d_in[7];
    const float* Wp2 = (const float*)d_in[8];
    const float* bp2 = (const float*)d_in[9];
    float* out = (float*)d_out;

    char* ws = (char*)d_ws;
    // binned = NBINS*BIN_STRIDE*4 = 14,413,824 B (slot count, not edge count!)
    int*    bin_cursor = (int*)   (ws + 0);          //  1,568 B (incl. done ctr)
    int*    bin_base   = (int*)   (ws + 2048);       //  1,564 B
    int*    rowptr     = (int*)   (ws + 4096);       //  400,004 B
    float*  dn         = (float*) (ws + 404480);     //  400,000 B
    int*    csr        = (int*)   (ws + 804608);     //  12,800,000 B -> ends 13,604,608
    uint*   binned     = (uint*)  (ws + 13604608);   //  14,413,824 B -> ends 28,018,432
    uint*   H1h        = (uint*)  (ws + 28018432);   //  12,800,000 B -> ends 40,818,432
    ushort* H2h        = (ushort*)(ws + 40818432);   //   6,400,000 B -> ends 47,218,432

    hipMemsetAsync(bin_cursor, 0, (NBINS + 1) * sizeof(int), stream);

    k_bin<<<(N_EDGES + BIN_EPB - 1) / BIN_EPB, 512, 0, stream>>>(ei, bin_cursor, binned,
                                                                 bin_base, rowptr);
    k_csr<<<NBINS, 512, 0, stream>>>(binned, bin_cursor, bin_base, rowptr, dn, csr);
    k_gemm_h<IN_DIM, HID_DIM><<<(N_NODES + 127) / 128, 256, 0, stream>>>(x, W1, H1h, N_NODES);

    k_agg1<<<(N_NODES / 2 + 3) / 4, 256, 0, stream>>>(H1h, rowptr, csr, dn, b1, W2, H2h);
    k_agg2m<<<(N_NODES / 2 + 3) / 4, 256, 0, stream>>>((const uint*)H2h, rowptr, csr, dn, b2,
                                                       Wp1, bp1, Wp2, bp2,
                                                       out, out + (size_t)N_NODES * OUT_DIM);
}

// Round 20
// 278.738 us; speedup vs baseline: 1.2466x; 1.0576x over previous
//
#include <hip/hip_runtime.h>
#include <hip/hip_fp16.h>
#include <cstdint>
#include <cstddef>

#define N_NODES 100000
#define N_EDGES 3200000
#define IN_DIM  256
#define HID_DIM 64
#define OUT_DIM 32

#define NBINS      391        // ceil(100000/256), 256 nodes per bin
#define BIN_SHIFT  8
#define BIN_STRIDE 9216       // lambda=8192, +11 sigma headroom
#define BIN_EPB    8192

typedef unsigned int uint;
typedef unsigned char uchar;
typedef unsigned short ushort;

__device__ __forceinline__ float2 h2tof2(uint u) {
    __half2 h = *reinterpret_cast<const __half2*>(&u);
    return __half22float2(h);
}
__device__ __forceinline__ uint f2toh2(float a, float b) {
    __half2 h = __floats2half2_rn(a, b);
    return *reinterpret_cast<const uint*>(&h);
}
__device__ __forceinline__ ushort f2h(float a) {
    __half h = __float2half_rn(a);
    return *reinterpret_cast<const ushort*>(&h);
}
// acc = fma(w, (float)fp16_lo/hi(v), acc) — exact cvt, bit-identical to cvt+fmaf.
__device__ __forceinline__ void fma_mix_lo(float& acc, float w, uint v) {
    asm("v_fma_mix_f32 %0, %1, %2, %0 op_sel:[0,0,0] op_sel_hi:[0,1,0]"
        : "+v"(acc) : "v"(w), "v"(v));
}
__device__ __forceinline__ void fma_mix_hi(float& acc, float w, uint v) {
    asm("v_fma_mix_f32 %0, %1, %2, %0 op_sel:[0,1,0] op_sel_hi:[0,1,0]"
        : "+v"(acc) : "v"(w), "v"(v));
}

// ---------------- pass 1: bin edges by dst>>8 (packed uint), inline last-block scan ----------------
// Global-load loops batched 4-deep (latency fix; loads issued together).
__global__ __launch_bounds__(512)
void k_bin(const int* __restrict__ ei, int* __restrict__ bin_cursor,
           uint* __restrict__ binned, int* __restrict__ bin_base,
           int* __restrict__ rowptr) {
    __shared__ int   lcount[NBINS];
    __shared__ int   lstart[NBINS];
    __shared__ int   lplace[NBINS];
    __shared__ int   gbase[NBINS];
    __shared__ int   sc[512];
    __shared__ uint  stage[BIN_EPB];    // 32 KB
    __shared__ uchar binid[BIN_EPB];    //  8 KB

    const int tid  = threadIdx.x;
    const int bid  = blockIdx.x;
    int*      done = bin_cursor + NBINS;   // zeroed by memset

    const int e0   = bid * BIN_EPB;
    const int nval = min(BIN_EPB, N_EDGES - e0);

    for (int i = tid; i < NBINS; i += 512) lcount[i] = 0;
    __syncthreads();

    // count pass: 16 edges/thread, batched 4-deep
    #pragma unroll
    for (int k = 0; k < BIN_EPB / 512; k += 4) {
        int d4[4];
        #pragma unroll
        for (int u = 0; u < 4; ++u) {
            int e = e0 + (k + u) * 512 + tid;
            d4[u] = (e < N_EDGES) ? ei[N_EDGES + e] : -1;
        }
        #pragma unroll
        for (int u = 0; u < 4; ++u)
            if (d4[u] >= 0) atomicAdd(&lcount[d4[u] >> BIN_SHIFT], 1);
    }
    __syncthreads();

    int v = (tid < NBINS) ? lcount[tid] : 0;
    sc[tid] = v; __syncthreads();
    for (int off = 1; off < 512; off <<= 1) {
        int x = sc[tid];
        if (tid >= off) x += sc[tid - off];
        __syncthreads(); sc[tid] = x; __syncthreads();
    }
    if (tid < NBINS) {
        int excl = sc[tid] - v;
        lstart[tid] = excl;
        lplace[tid] = excl;
        gbase[tid]  = atomicAdd(&bin_cursor[tid], v);
    }
    __syncthreads();

    // stage pass: batched 4-deep loads of (s,d)
    #pragma unroll
    for (int k = 0; k < BIN_EPB / 512; k += 4) {
        int s4[4], d4[4];
        #pragma unroll
        for (int u = 0; u < 4; ++u) {
            int e = e0 + (k + u) * 512 + tid;
            bool ok = (e < N_EDGES);
            s4[u] = ok ? ei[e] : -1;
            d4[u] = ok ? ei[N_EDGES + e] : 0;
        }
        #pragma unroll
        for (int u = 0; u < 4; ++u) {
            if (s4[u] >= 0) {
                int b = d4[u] >> BIN_SHIFT;
                int p = atomicAdd(&lplace[b], 1);
                stage[p] = (uint)s4[u] | ((uint)(d4[u] & 255) << 17)
                         | ((uint)(b >> 8) << 25);
                binid[p] = (uchar)(b & 255);
            }
        }
    }
    __syncthreads();

    for (int i = tid; i < nval; i += 512) {
        uint ed = stage[i];
        int  b  = (int)binid[i] | (int)((ed >> 25) & 1u) << 8;
        int  gix = gbase[b] + (i - lstart[b]);
        if (gix < BIN_STRIDE)
            binned[(size_t)b * BIN_STRIDE + gix] = ed;
    }
    __syncthreads();

    // ---- last-block inline binscan ----
    if (tid == 0) {
        __threadfence();
        lcount[0] = (atomicAdd(done, 1) == gridDim.x - 1) ? 1 : 0;
    }
    __syncthreads();
    if (lcount[0]) {
        int t = tid;
        int vv = 0;
        if (t < NBINS) vv = min(atomicAdd(&bin_cursor[t], 0), BIN_STRIDE);
        sc[t] = vv; __syncthreads();
        for (int off = 1; off < 512; off <<= 1) {
            int x = sc[t];
            if (t >= off) x += sc[t - off];
            __syncthreads(); sc[t] = x; __syncthreads();
        }
        if (t < NBINS)      bin_base[t] = sc[t] - vv;
        if (t == NBINS - 1) rowptr[N_NODES] = sc[t];
    }
}

// ---------------- pass 2: per-bin LDS counting sort -> CSR (+dn), 512 thr, batched ----------------
__global__ __launch_bounds__(512)
void k_csr(const uint* __restrict__ binned, const int* __restrict__ bin_cursor,
           const int* __restrict__ bin_base, int* __restrict__ rowptr,
           float* __restrict__ dn, int* __restrict__ csr) {
    __shared__ int lcnt[256];
    __shared__ int lpl[256];
    __shared__ int sc[256];
    __shared__ int csr_s[BIN_STRIDE];   // 36.9 KB

    const int tid   = threadIdx.x;
    const int b     = blockIdx.x;
    const int n0    = b << BIN_SHIFT;
    const int cnt   = min(bin_cursor[b], BIN_STRIDE);
    const int ebase = bin_base[b];
    const uint* bb  = binned + (size_t)b * BIN_STRIDE;

    if (tid < 256) lcnt[tid] = 0;
    __syncthreads();

    // count pass, 4-deep batched loads
    for (int i0 = tid; i0 < cnt; i0 += 2048) {
        uint e4[4]; int ok[4];
        #pragma unroll
        for (int u = 0; u < 4; ++u) {
            int i = i0 + u * 512;
            ok[u] = (i < cnt);
            e4[u] = bb[ok[u] ? i : 0];
        }
        #pragma unroll
        for (int u = 0; u < 4; ++u)
            if (ok[u]) atomicAdd(&lcnt[(e4[u] >> 17) & 255u], 1);
    }
    __syncthreads();

    int v = 0;
    if (tid < 256) { v = lcnt[tid]; sc[tid] = v; }
    __syncthreads();
    for (int off = 1; off < 256; off <<= 1) {
        int x = 0;
        if (tid < 256) { x = sc[tid]; if (tid >= off) x += sc[tid - off]; }
        __syncthreads();
        if (tid < 256) sc[tid] = x;
        __syncthreads();
    }
    if (tid < 256) {
        int excl = sc[tid] - v;
        lpl[tid] = excl;
        int n = n0 + tid;
        if (n < N_NODES) {
            rowptr[n] = ebase + excl;
            dn[n]     = rsqrtf((float)v + 1.0f);   // +1 self-loop
        }
    }
    __syncthreads();

    // placement pass, 4-deep batched loads
    for (int i0 = tid; i0 < cnt; i0 += 2048) {
        uint e4[4]; int ok[4];
        #pragma unroll
        for (int u = 0; u < 4; ++u) {
            int i = i0 + u * 512;
            ok[u] = (i < cnt);
            e4[u] = bb[ok[u] ? i : 0];
        }
        #pragma unroll
        for (int u = 0; u < 4; ++u) {
            if (ok[u]) {
                int p = atomicAdd(&lpl[(e4[u] >> 17) & 255u], 1);
                csr_s[p] = (int)(e4[u] & 0x1FFFFu);
            }
        }
    }
    __syncthreads();
    for (int i = tid; i < cnt; i += 512)
        csr[ebase + i] = csr_s[i];
}

// ---------------- tiled fp32 GEMM: Y[M,NC] = X[M,KD] @ W[KD,NC], fp16 output ----------------
template<int KD, int NC>
__global__ __launch_bounds__(32 * (NC / 8))
void k_gemm_h(const float* __restrict__ X, const float* __restrict__ W,
              uint* __restrict__ Yh, int M) {
    constexpr int TC = NC / 8;
    constexpr int THREADS = 32 * TC;
    constexpr int KC = 32;
    __shared__ float Xs[128][33];
    __shared__ float Ws[KC][NC];

    const int tid  = threadIdx.x;
    const int tr   = tid / TC;
    const int tc   = tid % TC;
    const int row0 = blockIdx.x * 128;

    float acc[4][8];
    #pragma unroll
    for (int i = 0; i < 4; ++i)
        #pragma unroll
        for (int j = 0; j < 8; ++j) acc[i][j] = 0.f;

    for (int kc = 0; kc < KD; kc += KC) {
        #pragma unroll
        for (int i = tid; i < 128 * (KC / 4); i += THREADS) {
            int r  = i / (KC / 4);
            int k4 = (i % (KC / 4)) * 4;
            float4 v = make_float4(0.f, 0.f, 0.f, 0.f);
            int gr = row0 + r;
            if (gr < M)
                v = *reinterpret_cast<const float4*>(&X[(size_t)gr * KD + kc + k4]);
            Xs[r][k4 + 0] = v.x; Xs[r][k4 + 1] = v.y;
            Xs[r][k4 + 2] = v.z; Xs[r][k4 + 3] = v.w;
        }
        #pragma unroll
        for (int i = tid; i < KC * (NC / 4); i += THREADS) {
            int kk = i / (NC / 4);
            int c4 = (i % (NC / 4)) * 4;
            *reinterpret_cast<float4*>(&Ws[kk][c4]) =
                *reinterpret_cast<const float4*>(&W[(size_t)(kc + kk) * NC + c4]);
        }
        __syncthreads();

        #pragma unroll
        for (int kk = 0; kk < KC; ++kk) {
            float xv[4];
            #pragma unroll
            for (int i = 0; i < 4; ++i) xv[i] = Xs[tr * 4 + i][kk];
            float4 w0 = *reinterpret_cast<const float4*>(&Ws[kk][tc * 8]);
            float4 w1 = *reinterpret_cast<const float4*>(&Ws[kk][tc * 8 + 4]);
            float wv[8] = {w0.x, w0.y, w0.z, w0.w, w1.x, w1.y, w1.z, w1.w};
            #pragma unroll
            for (int i = 0; i < 4; ++i)
                #pragma unroll
                for (int j = 0; j < 8; ++j)
                    acc[i][j] = fmaf(xv[i], wv[j], acc[i][j]);
        }
        __syncthreads();
    }

    #pragma unroll
    for (int i = 0; i < 4; ++i) {
        int gr = row0 + tr * 4 + i;
        if (gr < M) {
            uint4 o;
            o.x = f2toh2(acc[i][0], acc[i][1]);
            o.y = f2toh2(acc[i][2], acc[i][3]);
            o.z = f2toh2(acc[i][4], acc[i][5]);
            o.w = f2toh2(acc[i][6], acc[i][7]);
            *reinterpret_cast<uint4*>(&Yh[(size_t)gr * (NC / 2) + tc * 4]) = o;
        }
    }
}

// ---------------- agg1 (+bias+relu) fused with GEMM2 -> H2 (fp16) ----------------
// TWO nodes per wave (r12/r14/r16 verbatim, passing); fp16x2 gathers; fp32
// accum via v_fma_mix. Per-feature chain: self first, edges ascending in CSR
// order, single accumulator; idle slots exact fma(0,.). 8-deep load batching
// (the verified occupancy sweet spot: 40 VGPR, ~59% occ).
__global__ __launch_bounds__(256)
void k_agg1(const uint* __restrict__ H1h, const int* __restrict__ rowptr,
            const int* __restrict__ csr, const float* __restrict__ dn,
            const float* __restrict__ b1, const float* __restrict__ W2,
            ushort* __restrict__ H2h) {
    __shared__ float W2s[HID_DIM * OUT_DIM];   // 8 KB
    for (int i = threadIdx.x; i < HID_DIM * OUT_DIM; i += 256) W2s[i] = W2[i];
    __syncthreads();

    int wid  = (blockIdx.x * blockDim.x + threadIdx.x) >> 6;
    int lane = threadIdx.x & 63;
    if (wid >= N_NODES / 2) return;
    const int half = lane >> 5;
    const int hb   = half << 5;
    const int l    = lane & 31;
    const int n    = 2 * wid + half;

    int rp = (l < 2) ? rowptr[n + l] : 0;
    int base = __shfl(rp, hb + 0);
    int cnt  = __shfl(rp, hb + 1) - base;
    const float dnn = dn[n];

    float2 self2 = h2tof2(H1h[(size_t)n * 32 + l]);
    float2 acc;
    acc.x = dnn * self2.x;
    acc.y = dnn * self2.y;

    const int cnt2 = max(cnt, __shfl_xor(cnt, 32));
    for (int b0 = 0; b0 < cnt2; b0 += 32) {
        int m_own = min(32, cnt - b0);
        int m_max = min(32, cnt2 - b0);
        int s = 0; float dsv = 0.f;
        if (l < m_own) { s = csr[base + b0 + l]; dsv = dn[s]; }
        for (int j0 = 0; j0 < m_max; j0 += 8) {
            uint v[8]; float w[8];
            #pragma unroll
            for (int i = 0; i < 8; ++i) {
                int j  = j0 + i;
                int sj = __shfl(s, hb + j);
                w[i] = __shfl(dsv, hb + j);
                v[i] = H1h[(size_t)sj * 32 + l];
            }
            #pragma unroll
            for (int i = 0; i < 8; ++i) {
                fma_mix_lo(acc.x, w[i], v[i]);
                fma_mix_hi(acc.y, w[i], v[i]);
            }
        }
    }
    float2 b1q = *reinterpret_cast<const float2*>(b1 + 2 * l);
    float2 o;
    o.x = fmaxf(b1q.x + dnn * acc.x, 0.f);
    o.y = fmaxf(b1q.y + dnn * acc.y, 0.f);

    const int c = lane & 31, hh = lane >> 5;
    #pragma unroll
    for (int nodesel = 0; nodesel < 2; ++nodesel) {
        const int nb = nodesel << 5;
        float acc2 = 0.f;
        #pragma unroll
        for (int fi = 0; fi < 32; ++fi) {
            int f = hh * 32 + fi;
            float vv = (f & 1) ? __shfl(o.y, nb + (f >> 1))
                               : __shfl(o.x, nb + (f >> 1));
            acc2 = fmaf(vv, W2s[f * OUT_DIM + c], acc2);
        }
        acc2 += __shfl_xor(acc2, 32);
        if (hh == 0) H2h[(size_t)(2 * wid + nodesel) * 32 + c] = f2h(acc2);
    }
}

// ---------------- agg2 (+bias) fused with MLP head ----------------
// TWO nodes per wave (r12/r14/r16 verbatim, passing), fp16x2 gathers + fma_mix.
__global__ __launch_bounds__(256)
void k_agg2m(const uint* __restrict__ H2h, const int* __restrict__ rowptr,
             const int* __restrict__ csr, const float* __restrict__ dn,
             const float* __restrict__ b2, const float* __restrict__ Wp1,
             const float* __restrict__ bp1, const float* __restrict__ Wp2,
             const float* __restrict__ bp2, float* __restrict__ out_h,
             float* __restrict__ out_w) {
    __shared__ float Wp1s[OUT_DIM * HID_DIM];  // 8 KB
    __shared__ float Wp2s[HID_DIM];
    __shared__ float bp1s[HID_DIM];
    for (int i = threadIdx.x; i < OUT_DIM * HID_DIM; i += 256) Wp1s[i] = Wp1[i];
    if (threadIdx.x < HID_DIM) {
        Wp2s[threadIdx.x] = Wp2[threadIdx.x];
        bp1s[threadIdx.x] = bp1[threadIdx.x];
    }
    __syncthreads();

    int wid  = (blockIdx.x * blockDim.x + threadIdx.x) >> 6;
    int lane = threadIdx.x & 63;
    if (wid >= N_NODES / 2) return;
    const int nd  = lane >> 5;
    const int nb0 = nd << 5;
    const int l32 = lane & 31;
    const int l   = lane & 15;
    const int h2  = (lane >> 4) & 1;
    const int n   = 2 * wid + nd;

    int rp = (lane < 3) ? rowptr[2 * wid + lane] : 0;
    int base = __shfl(rp, nd);
    int cnt  = __shfl(rp, nd + 1) - base;
    const float dnn = dn[n];

    float2 self2 = h2tof2(H2h[(size_t)n * 16 + l]);
    float2 acc;
    acc.x = (h2 == 0) ? dnn * self2.x : 0.f;
    acc.y = (h2 == 0) ? dnn * self2.y : 0.f;

    const int cnt2 = max(cnt, __shfl_xor(cnt, 32));
    for (int b0 = 0; b0 < cnt2; b0 += 32) {
        int m_own = min(32, cnt - b0);
        int m_max = min(32, cnt2 - b0);
        int s = 0; float dsv = 0.f;
        if (l32 < m_own) { s = csr[base + b0 + l32]; dsv = dn[s]; }
        for (int j0 = h2; j0 < m_max; j0 += 16) {
            uint v[8]; float w[8];
            #pragma unroll
            for (int i = 0; i < 8; ++i) {
                int j  = j0 + 2 * i;              // <= j0+14 <= 31
                int sj = __shfl(s, nb0 + j);
                w[i] = __shfl(dsv, nb0 + j);      // 0 when j >= m_own
                v[i] = H2h[(size_t)sj * 16 + l];
            }
            #pragma unroll
            for (int i = 0; i < 8; ++i) {
                fma_mix_lo(acc.x, w[i], v[i]);
                fma_mix_hi(acc.y, w[i], v[i]);
            }
        }
    }
    acc.x += __shfl_xor(acc.x, 16);               // even + odd (r5 association)
    acc.y += __shfl_xor(acc.y, 16);
    float2 b2q = *reinterpret_cast<const float2*>(b2 + 2 * l);
    float2 hv;
    hv.x = b2q.x + dnn * acc.x;
    hv.y = b2q.y + dnn * acc.y;
    if (h2 == 0)
        *reinterpret_cast<float2*>(out_h + (size_t)n * OUT_DIM + 2 * l) = hv;

    // MLP head per node: p[j]=relu(bp1[j]+sum_ff h_ff Wp1[ff][j])
    #pragma unroll
    for (int nodesel = 0; nodesel < 2; ++nodesel) {
        const int nb = nodesel << 5;
        float p = bp1s[lane];
        #pragma unroll
        for (int ff = 0; ff < OUT_DIM; ++ff) {
            float hf = (ff & 1) ? __shfl(hv.y, nb + (ff >> 1))
                                : __shfl(hv.x, nb + (ff >> 1));
            p = fmaf(hf, Wp1s[ff * HID_DIM + lane], p);
        }
        p = fmaxf(p, 0.f);
        float z = p * Wp2s[lane];
        #pragma unroll
        for (int off = 32; off; off >>= 1) z += __shfl_xor(z, off);
        if (lane == 0)
            out_w[2 * wid + nodesel] = 1.f / (1.f + __expf(-(z + bp2[0])));
    }
}

// ---------------- launcher ----------------
extern "C" void kernel_launch(void* const* d_in, const int* in_sizes, int n_in,
                              void* d_out, int out_size, void* d_ws, size_t ws_size,
                              hipStream_t stream) {
    const float* x   = (const float*)d_in[0];
    const int*   ei  = (const int*)d_in[1];
    const float* W1  = (const float*)d_in[2];
    const float* b1  = (const float*)d_in[3];
    const float* W2  = (const float*)d_in[4];
    const float* b2  = (const float*)d_in[5];
    const float* Wp1 = (const float*)d_in[6];
    const float* bp1 = (const float*)d_in[7];
    const float* Wp2 = (const float*)d_in[8];
    const float* bp2 = (const float*)d_in[9];
    float* out = (float*)d_out;

    char* ws = (char*)d_ws;
    // binned = NBINS*BIN_STRIDE*4 = 14,413,824 B (slot count, not edge count!)
    int*    bin_cursor = (int*)   (ws + 0);          //  1,568 B (incl. done ctr)
    int*    bin_base   = (int*)   (ws + 2048);       //  1,564 B
    int*    rowptr     = (int*)   (ws + 4096);       //  400,004 B
    float*  dn         = (float*) (ws + 404480);     //  400,000 B
    int*    csr        = (int*)   (ws + 804608);     //  12,800,000 B -> ends 13,604,608
    uint*   binned     = (uint*)  (ws + 13604608);   //  14,413,824 B -> ends 28,018,432
    uint*   H1h        = (uint*)  (ws + 28018432);   //  12,800,000 B -> ends 40,818,432
    ushort* H2h        = (ushort*)(ws + 40818432);   //   6,400,000 B -> ends 47,218,432

    hipMemsetAsync(bin_cursor, 0, (NBINS + 1) * sizeof(int), stream);

    k_bin<<<(N_EDGES + BIN_EPB - 1) / BIN_EPB, 512, 0, stream>>>(ei, bin_cursor, binned,
                                                                 bin_base, rowptr);
    k_csr<<<NBINS, 512, 0, stream>>>(binned, bin_cursor, bin_base, rowptr, dn, csr);
    k_gemm_h<IN_DIM, HID_DIM><<<(N_NODES + 127) / 128, 256, 0, stream>>>(x, W1, H1h, N_NODES);

    k_agg1<<<(N_NODES / 2 + 3) / 4, 256, 0, stream>>>(H1h, rowptr, csr, dn, b1, W2, H2h);
    k_agg2m<<<(N_NODES / 2 + 3) / 4, 256, 0, stream>>>((const uint*)H2h, rowptr, csr, dn, b2,
                                                       Wp1, bp1, Wp2, bp2,
                                                       out, out + (size_t)N_NODES * OUT_DIM);
}